// Round 7
// baseline (2154.097 us; speedup 1.0000x reference)
//
#include <hip/hip_runtime.h>
#include <cstdint>
#include <cstddef>

using u16 = unsigned short;
using bf16x8 = __attribute__((ext_vector_type(8))) __bf16;
using f32x4  = __attribute__((ext_vector_type(4))) float;

static __device__ __forceinline__ u16 f2bf(float f) {
  unsigned u = __builtin_bit_cast(unsigned, f);
  unsigned r = (u + 0x7fffu + ((u >> 16) & 1u)) >> 16;  // RNE
  return (u16)r;
}
static __device__ __forceinline__ float bf2f(u16 h) {
  unsigned u = ((unsigned)h) << 16;
  return __builtin_bit_cast(float, u);
}
static __device__ __forceinline__ float eluf(float x) {
  return x > 0.f ? x : expm1f(x);
}
static __device__ __forceinline__ void gload16(const u16* g, u16* l) {
  __builtin_amdgcn_global_load_lds(
      (const __attribute__((address_space(1))) void*)g,
      (__attribute__((address_space(3))) void*)l, 16, 0, 0);
}

// ---------------------------------------------------------------------------
// Weight transpose+convert: src (E, Ksrc, Nsrc) f32  ->  dst bf16 (Nsrc*E, Kpad)
// ---------------------------------------------------------------------------
__global__ void transpose_convert(const float* __restrict__ src, u16* __restrict__ dst,
                                  int Ksrc, int Nsrc, int Kpad, int E) {
  __shared__ float tile[32][33];
  const int e  = blockIdx.z;
  const int k0 = blockIdx.x * 32;
  const int d0 = blockIdx.y * 32;
  const int tx = threadIdx.x;  // 0..31
  const int ty = threadIdx.y;  // 0..7
  const float* s = src + (size_t)e * Ksrc * Nsrc;
#pragma unroll
  for (int i = 0; i < 4; ++i) {
    const int k = k0 + ty + i * 8;
    float v = 0.f;
    if (k < Ksrc) v = s[(size_t)k * Nsrc + d0 + tx];
    tile[ty + i * 8][tx] = v;
  }
  __syncthreads();
#pragma unroll
  for (int i = 0; i < 4; ++i) {
    const int d = d0 + ty + i * 8;
    dst[((size_t)d * E + e) * Kpad + k0 + tx] = f2bf(tile[tx][ty + i * 8]);
  }
}

// ---------------------------------------------------------------------------
// Build bf16 concat buffers.
// ---------------------------------------------------------------------------
__global__ void prep_cat(const float* __restrict__ z, const float* __restrict__ p,
                         const float* __restrict__ vh, const float* __restrict__ xc,
                         u16* __restrict__ catP, u16* __restrict__ catE0,
                         u16* __restrict__ cat0, u16* __restrict__ cat1) {
  const int m = blockIdx.x;
  const int t = threadIdx.x;  // 0..255
  const u16 zb = f2bf(z[(size_t)m * 256 + t]);
  catP [(size_t)m * 288 + t] = zb;
  catE0[(size_t)m * 576 + t] = zb;
  cat0 [(size_t)m * 768 + t] = zb;
  cat1 [(size_t)m * 768 + t] = zb;
  if (t < 32) {
    const u16 val = (t < 16) ? f2bf(p[(size_t)m * 16 + t]) : (u16)0;
    catP[(size_t)m * 288 + 256 + t] = val;
  }
  for (int c = 256 + t; c < 576; c += 256) {
    const int idx = c - 256;
    float v = 0.f;
    if (idx < 3)        v = vh[(size_t)m * 3 + idx];
    else if (idx < 259) v = xc[(size_t)m * 256 + (idx - 3)];
    catE0[(size_t)m * 576 + c] = f2bf(v);
  }
}

// ---------------------------------------------------------------------------
// Gating layer 2 (N=8) + softmax: one wave per token.
// ---------------------------------------------------------------------------
__global__ __launch_bounds__(256) void gating_tail(const u16* __restrict__ cat,
                                                   const float* __restrict__ gw2,
                                                   const float* __restrict__ gb2,
                                                   float* __restrict__ ew) {
  const int ln = threadIdx.x & 63;
  const int token = (int)((blockIdx.x * 256 + threadIdx.x) >> 6);
  const u16* row = cat + (size_t)token * 768;
  float a[8] = {0.f, 0.f, 0.f, 0.f, 0.f, 0.f, 0.f, 0.f};
#pragma unroll
  for (int kk = 0; kk < 12; ++kk) {
    const int k = kk * 64 + ln;
    const float x = bf2f(row[k]);
    const float4* wr = reinterpret_cast<const float4*>(gw2 + (size_t)k * 8);
    const float4 w0 = wr[0], w1 = wr[1];
    a[0] += x * w0.x; a[1] += x * w0.y; a[2] += x * w0.z; a[3] += x * w0.w;
    a[4] += x * w1.x; a[5] += x * w1.y; a[6] += x * w1.z; a[7] += x * w1.w;
  }
#pragma unroll
  for (int j = 0; j < 8; ++j) {
#pragma unroll
    for (int d = 32; d > 0; d >>= 1) a[j] += __shfl_xor(a[j], d);
    a[j] += gb2[j];
  }
  float mx = a[0];
#pragma unroll
  for (int j = 1; j < 8; ++j) mx = fmaxf(mx, a[j]);
  float s = 0.f, pj[8];
#pragma unroll
  for (int j = 0; j < 8; ++j) { pj[j] = expf(a[j] - mx); s += pj[j]; }
  const float inv = 1.f / s;
  if (ln == 0) {
#pragma unroll
    for (int j = 0; j < 8; ++j) ew[(size_t)token * 8 + j] = pj[j] * inv;
  }
}

// ---------------------------------------------------------------------------
// 128x128 bf16 MFMA GEMM (gating layers only; small fraction of runtime).
// ---------------------------------------------------------------------------
template <int MODE, int BK>
__global__ __launch_bounds__(256) void gemm_mfma(
    const u16* __restrict__ A, const u16* __restrict__ Bt,
    const float* __restrict__ bias, const float* __restrict__ ew,
    void* __restrict__ outp, int M, int N, int K,
    int out_stride, int out_col0) {
  constexpr int SLOTS = BK / 8;
  constexpr int SSH   = (BK == 32) ? 2 : 3;
  constexpr int CROWS = 1024 / (BK * 2);
  constexpr int LOADS = BK / 16;

  __shared__ alignas(16) u16 As[128 * BK];
  __shared__ alignas(16) u16 Bs[128 * BK];

  const int tid = threadIdx.x;
  const int ln  = tid & 63;
  const int wv  = tid >> 6;
  const int wr  = wv >> 1;
  const int wc  = wv & 1;
  const int m0  = blockIdx.y * 128;
  const int n0  = blockIdx.x * 128;

  const int lrow  = ln >> SSH;
  const int lslot = ln & (SLOTS - 1);
  const int fw    = (BK == 64) ? (lrow & 7) : ((lrow >> 1) & 3);
  const int gcol  = ((lslot ^ fw) << 3);
  const int c0    = wv * LOADS;

  const u16* gA[LOADS]; const u16* gB[LOADS];
  u16* lA[LOADS]; u16* lB[LOADS];
#pragma unroll
  for (int t = 0; t < LOADS; ++t) {
    const int rowg = (c0 + t) * CROWS + lrow;
    gA[t] = A  + (size_t)(m0 + rowg) * K + gcol;
    gB[t] = Bt + (size_t)(n0 + rowg) * K + gcol;
    lA[t] = &As[(size_t)(c0 + t) * 512];
    lB[t] = &Bs[(size_t)(c0 + t) * 512];
  }

  f32x4 acc[4][4];
#pragma unroll
  for (int i = 0; i < 4; ++i)
#pragma unroll
    for (int j = 0; j < 4; ++j) acc[i][j] = (f32x4){0.f, 0.f, 0.f, 0.f};

  const int ar  = ln & 15;
  const int hi  = ln >> 4;
  const int arf = (BK == 64) ? (ar & 7) : ((ar >> 1) & 3);

  const int kIters = K / BK;
  for (int kt = 0; kt < kIters; ++kt) {
#pragma unroll
    for (int t = 0; t < LOADS; ++t) gload16(gA[t], lA[t]);
#pragma unroll
    for (int t = 0; t < LOADS; ++t) gload16(gB[t], lB[t]);
#pragma unroll
    for (int t = 0; t < LOADS; ++t) { gA[t] += BK; gB[t] += BK; }
    __syncthreads();

#pragma unroll
    for (int k32 = 0; k32 < BK / 32; ++k32) {
      bf16x8 af[4], bfv[4];
#pragma unroll
      for (int i = 0; i < 4; ++i)
        af[i] = *reinterpret_cast<const bf16x8*>(
            &As[(size_t)(wr * 64 + i * 16 + ar) * BK + (((k32 * 4 + hi) ^ arf) << 3)]);
#pragma unroll
      for (int j = 0; j < 4; ++j)
        bfv[j] = *reinterpret_cast<const bf16x8*>(
            &Bs[(size_t)(wc * 64 + j * 16 + ar) * BK + (((k32 * 4 + hi) ^ arf) << 3)]);
#pragma unroll
      for (int i = 0; i < 4; ++i)
#pragma unroll
        for (int j = 0; j < 4; ++j)
          acc[i][j] = __builtin_amdgcn_mfma_f32_16x16x32_bf16(af[i], bfv[j], acc[i][j], 0, 0, 0);
    }
    __syncthreads();
  }

  const int m0w = m0 + wr * 64 + (ln >> 4) * 4;
  const int n0w = n0 + wc * 64 + (ln & 15);
  u16* outb = (u16*)outp;
#pragma unroll
  for (int j = 0; j < 4; ++j) {
    const int n = n0w + j * 16;
    const float bv = bias[n];
#pragma unroll
    for (int i = 0; i < 4; ++i) {
#pragma unroll
      for (int r = 0; r < 4; ++r) {
        const int m = m0w + i * 16 + r;
        outb[(size_t)m * out_stride + out_col0 + n] = f2bf(eluf(acc[i][j][r] + bv));
      }
    }
  }
}

// ---------------------------------------------------------------------------
// Expert GEMM: 256x256 tile, 8 waves (2Mx4N), BK=64, SINGLE-buffered LDS
// (64 KiB -> 2 blocks/CU; inter-block overlap covers the per-tile vmcnt(0)
// drain, the m97/m114 mechanism). 2-phase loop: stage -> sync -> 64 MFMA ->
// sync. 32 MFMA per barrier. XCD-aware block swizzle (T1): 1D grid, bid&7 =
// XCD, each XCD owns bxPerXcd consecutive B-panel columns (L2-resident) and
// iterates M-rows within them.
// LDS XOR-swizzle both-sides (slot ^= row&7), linear gload_lds dest +
// pre-swizzled global source.
// MODE 1: n = dout*8+e; out = elu(sum_e ew[m,e]*(acc+bias[e*Dout+dout])), bf16.
// MODE 2: same but fp32 write, no elu (final layer).
// ---------------------------------------------------------------------------
template <int MODE>
__global__ __launch_bounds__(512, 4) void gemm256s(
    const u16* __restrict__ A, const u16* __restrict__ Bt,
    const float* __restrict__ bias, const float* __restrict__ ew,
    void* __restrict__ outp, int N, int K, int out_stride, int out_col0,
    int bxPerXcd) {
  constexpr int BK = 64;
  __shared__ alignas(16) u16 As[256 * BK];  // 32 KiB
  __shared__ alignas(16) u16 Bs[256 * BK];  // 32 KiB

  const int tid = threadIdx.x;
  const int ln  = tid & 63;
  const int wv  = tid >> 6;     // 0..7
  const int wr  = wv >> 2;      // 0..1  (M half)
  const int wc  = wv & 3;       // 0..3  (N quarter)

  // XCD-aware decode: bid&7 = XCD; each XCD owns bxPerXcd adjacent N-tiles.
  const int bid = blockIdx.x;
  const int xcd = bid & 7;
  const int s   = bid >> 3;
  const int bx  = xcd * bxPerXcd + (s % bxPerXcd);
  const int by  = s / bxPerXcd;
  const int m0  = by * 256;
  const int n0  = bx * 256;

  // staging: wave wv stages chunks wv*4+q (q=0..3); chunk = 8 rows x 64 col
  const int lrow  = ln >> 3;          // 0..7 row within chunk
  const int gslot = (ln & 7) ^ lrow;  // pre-swizzled 16B slot within row
  const u16* gA[4]; const u16* gB[4];
#pragma unroll
  for (int q = 0; q < 4; ++q) {
    const int row = (wv * 4 + q) * 8 + lrow;
    gA[q] = A  + (size_t)(m0 + row) * K + gslot * 8;
    gB[q] = Bt + (size_t)(n0 + row) * K + gslot * 8;
  }

  f32x4 acc[8][4];
#pragma unroll
  for (int i = 0; i < 8; ++i)
#pragma unroll
    for (int j = 0; j < 4; ++j) acc[i][j] = (f32x4){0.f, 0.f, 0.f, 0.f};

  const int ar  = ln & 15;
  const int hi  = ln >> 4;       // 0..3
  const int arf = ar & 7;        // read-side swizzle
  const int sl0 = (hi ^ arf) << 3;        // kk=0 u16 offset
  const int sl1 = ((4 + hi) ^ arf) << 3;  // kk=1 u16 offset

  const int nt = K / BK;

  for (int t = 0; t < nt; ++t) {
#pragma unroll
    for (int q = 0; q < 4; ++q) {
      gload16(gA[q], &As[(size_t)((wv * 4 + q) * 8) * 64]);
      gload16(gB[q], &Bs[(size_t)((wv * 4 + q) * 8) * 64]);
      gA[q] += BK; gB[q] += BK;
    }
    __syncthreads();  // drains vmcnt(0)+lgkmcnt(0): tile staged & visible

    const u16* Ab = &As[(size_t)(wr * 128 + ar) * BK];
    const u16* Bb = &Bs[(size_t)(wc * 64 + ar) * BK];
#pragma unroll
    for (int kk = 0; kk < 2; ++kk) {
      const int sl = kk ? sl1 : sl0;
      bf16x8 bv[4], av[8];
#pragma unroll
      for (int j = 0; j < 4; ++j)
        bv[j] = *reinterpret_cast<const bf16x8*>(Bb + (size_t)j * 16 * BK + sl);
#pragma unroll
      for (int i = 0; i < 8; ++i)
        av[i] = *reinterpret_cast<const bf16x8*>(Ab + (size_t)i * 16 * BK + sl);
      __builtin_amdgcn_s_setprio(1);
#pragma unroll
      for (int i = 0; i < 8; ++i)
#pragma unroll
        for (int j = 0; j < 4; ++j)
          acc[i][j] = __builtin_amdgcn_mfma_f32_16x16x32_bf16(av[i], bv[j], acc[i][j], 0, 0, 0);
      __builtin_amdgcn_s_setprio(0);
    }
    __syncthreads();  // all reads done before next stage overwrites
  }

  // Epilogue. C/D: col = lane&15, row = (lane>>4)*4 + reg.
  const int e = ln & 7;                      // expert (j-invariant)
  const int m_base = m0 + wr * 128 + hi * 4;
  const int Dout = N >> 3;
  float ewv[32];
#pragma unroll
  for (int i = 0; i < 8; ++i)
#pragma unroll
    for (int r = 0; r < 4; ++r)
      ewv[i * 4 + r] = ew[(size_t)(m_base + i * 16 + r) * 8 + e];
#pragma unroll
  for (int j = 0; j < 4; ++j) {
    const int n = n0 + wc * 64 + j * 16 + (ln & 15);
    const int dout = n >> 3;
    const float bv = bias[(size_t)e * Dout + dout];
#pragma unroll
    for (int i = 0; i < 8; ++i) {
#pragma unroll
      for (int r = 0; r < 4; ++r) {
        const int m = m_base + i * 16 + r;
        float v = (acc[i][j][r] + bv) * ewv[i * 4 + r];
        v += __shfl_xor(v, 1);
        v += __shfl_xor(v, 2);
        v += __shfl_xor(v, 4);
        if ((ln & 7) == 0) {
          if (MODE == 1) {
            ((u16*)outp)[(size_t)m * out_stride + out_col0 + dout] = f2bf(eluf(v));
          } else {
            ((float*)outp)[(size_t)m * out_stride + dout] = v;
          }
        }
      }
    }
  }
}

// ---------------------------------------------------------------------------
extern "C" void kernel_launch(void* const* d_in, const int* in_sizes, int n_in,
                              void* d_out, int out_size, void* d_ws, size_t ws_size,
                              hipStream_t stream) {
  const float* z   = (const float*)d_in[0];
  const float* p   = (const float*)d_in[1];
  const float* vh  = (const float*)d_in[2];
  const float* xc  = (const float*)d_in[3];
  const float* gw0 = (const float*)d_in[4];
  const float* gb0 = (const float*)d_in[5];
  const float* gw1 = (const float*)d_in[6];
  const float* gb1 = (const float*)d_in[7];
  const float* gw2 = (const float*)d_in[8];
  const float* gb2 = (const float*)d_in[9];
  const float* w0  = (const float*)d_in[10];
  const float* b0  = (const float*)d_in[11];
  const float* w1  = (const float*)d_in[12];
  const float* b1  = (const float*)d_in[13];
  const float* w2  = (const float*)d_in[14];
  const float* b2  = (const float*)d_in[15];
  const float* wo  = (const float*)d_in[16];
  const float* bo  = (const float*)d_in[17];
  float* out = (float*)d_out;

  char* ws = (char*)d_ws;
  size_t off = 0;
  auto alloc = [&](size_t bytes) {
    char* pp = ws + off;
    off += (bytes + 255) & ~(size_t)255;
    return pp;
  };
  u16* gw0t  = (u16*)alloc((size_t)512 * 288 * 2);
  u16* gw1t  = (u16*)alloc((size_t)512 * 768 * 2);
  u16* w0t   = (u16*)alloc((size_t)4096 * 576 * 2);
  u16* w1t   = (u16*)alloc((size_t)4096 * 768 * 2);
  u16* w2t   = (u16*)alloc((size_t)4096 * 768 * 2);
  u16* wot   = (u16*)alloc((size_t)2048 * 768 * 2);
  u16* catP  = (u16*)alloc((size_t)8192 * 288 * 2);
  u16* catE0 = (u16*)alloc((size_t)8192 * 576 * 2);
  u16* cat0  = (u16*)alloc((size_t)8192 * 768 * 2);
  u16* cat1  = (u16*)alloc((size_t)8192 * 768 * 2);
  float* ew  = (float*)alloc((size_t)8192 * 8 * 4);
  (void)ws_size; (void)in_sizes; (void)n_in; (void)out_size;

  const dim3 tb(32, 8);
  transpose_convert<<<dim3(9, 16, 1),  tb, 0, stream>>>(gw0, gw0t, 272, 512, 288, 1);
  transpose_convert<<<dim3(24, 16, 1), tb, 0, stream>>>(gw1, gw1t, 768, 512, 768, 1);
  transpose_convert<<<dim3(18, 16, 8), tb, 0, stream>>>(w0,  w0t,  515, 512, 576, 8);
  transpose_convert<<<dim3(24, 16, 8), tb, 0, stream>>>(w1,  w1t,  768, 512, 768, 8);
  transpose_convert<<<dim3(24, 16, 8), tb, 0, stream>>>(w2,  w2t,  768, 512, 768, 8);
  transpose_convert<<<dim3(24, 8, 8),  tb, 0, stream>>>(wo,  wot,  768, 256, 768, 8);
  prep_cat<<<8192, 256, 0, stream>>>(z, p, vh, xc, catP, catE0, cat0, cat1);

  // gating (small: keep proven 128^2 kernel)
  gemm_mfma<0, 32><<<dim3(4, 64), 256, 0, stream>>>(catP, gw0t, gb0, nullptr, cat0,
                                                    8192, 512, 288, 768, 256);
  gemm_mfma<0, 64><<<dim3(4, 64), 256, 0, stream>>>(cat0, gw1t, gb1, nullptr, cat1,
                                                    8192, 512, 768, 768, 256);
  gating_tail<<<2048, 256, 0, stream>>>(cat1, gw2, gb2, ew);

  // expert layers: 256^2 single-buffered (64 KiB -> 2 blocks/CU), XCD-swizzled
  gemm256s<1><<<512, 512, 0, stream>>>(catE0, w0t, b0, ew, cat0,
                                       4096, 576, 768, 256, 2);
  gemm256s<1><<<512, 512, 0, stream>>>(cat0, w1t, b1, ew, cat1,
                                       4096, 768, 768, 256, 2);
  gemm256s<1><<<512, 512, 0, stream>>>(cat1, w2t, b2, ew, cat0,
                                       4096, 768, 768, 256, 2);
  gemm256s<2><<<256, 512, 0, stream>>>(cat0, wot, bo, ew, out,
                                       2048, 768, 256, 0, 1);
}

// Round 8
// 434.794 us; speedup vs baseline: 4.9543x; 4.9543x over previous
//
#include <hip/hip_runtime.h>
#include <cstdint>
#include <cstddef>

using u16 = unsigned short;
using bf16x8 = __attribute__((ext_vector_type(8))) __bf16;
using f32x4  = __attribute__((ext_vector_type(4))) float;

static __device__ __forceinline__ u16 f2bf(float f) {
  unsigned u = __builtin_bit_cast(unsigned, f);
  unsigned r = (u + 0x7fffu + ((u >> 16) & 1u)) >> 16;  // RNE
  return (u16)r;
}
static __device__ __forceinline__ float bf2f(u16 h) {
  unsigned u = ((unsigned)h) << 16;
  return __builtin_bit_cast(float, u);
}
static __device__ __forceinline__ float eluf(float x) {
  return x > 0.f ? x : expm1f(x);
}
static __device__ __forceinline__ void gload16(const u16* g, u16* l) {
  __builtin_amdgcn_global_load_lds(
      (const __attribute__((address_space(1))) void*)g,
      (__attribute__((address_space(3))) void*)l, 16, 0, 0);
}

// ---------------------------------------------------------------------------
// Weight transpose+convert: src (E, Ksrc, Nsrc) f32  ->  dst bf16 (Nsrc*E, Kpad)
// ---------------------------------------------------------------------------
__global__ void transpose_convert(const float* __restrict__ src, u16* __restrict__ dst,
                                  int Ksrc, int Nsrc, int Kpad, int E) {
  __shared__ float tile[32][33];
  const int e  = blockIdx.z;
  const int k0 = blockIdx.x * 32;
  const int d0 = blockIdx.y * 32;
  const int tx = threadIdx.x;  // 0..31
  const int ty = threadIdx.y;  // 0..7
  const float* s = src + (size_t)e * Ksrc * Nsrc;
#pragma unroll
  for (int i = 0; i < 4; ++i) {
    const int k = k0 + ty + i * 8;
    float v = 0.f;
    if (k < Ksrc) v = s[(size_t)k * Nsrc + d0 + tx];
    tile[ty + i * 8][tx] = v;
  }
  __syncthreads();
#pragma unroll
  for (int i = 0; i < 4; ++i) {
    const int d = d0 + ty + i * 8;
    dst[((size_t)d * E + e) * Kpad + k0 + tx] = f2bf(tile[tx][ty + i * 8]);
  }
}

// ---------------------------------------------------------------------------
// Build bf16 concat buffers.
// ---------------------------------------------------------------------------
__global__ void prep_cat(const float* __restrict__ z, const float* __restrict__ p,
                         const float* __restrict__ vh, const float* __restrict__ xc,
                         u16* __restrict__ catP, u16* __restrict__ catE0,
                         u16* __restrict__ cat0, u16* __restrict__ cat1) {
  const int m = blockIdx.x;
  const int t = threadIdx.x;  // 0..255
  const u16 zb = f2bf(z[(size_t)m * 256 + t]);
  catP [(size_t)m * 288 + t] = zb;
  catE0[(size_t)m * 576 + t] = zb;
  cat0 [(size_t)m * 768 + t] = zb;
  cat1 [(size_t)m * 768 + t] = zb;
  if (t < 32) {
    const u16 val = (t < 16) ? f2bf(p[(size_t)m * 16 + t]) : (u16)0;
    catP[(size_t)m * 288 + 256 + t] = val;
  }
  for (int c = 256 + t; c < 576; c += 256) {
    const int idx = c - 256;
    float v = 0.f;
    if (idx < 3)        v = vh[(size_t)m * 3 + idx];
    else if (idx < 259) v = xc[(size_t)m * 256 + (idx - 3)];
    catE0[(size_t)m * 576 + c] = f2bf(v);
  }
}

// ---------------------------------------------------------------------------
// Gating layer 2 (N=8) + softmax: one wave per token.
// ---------------------------------------------------------------------------
__global__ __launch_bounds__(256) void gating_tail(const u16* __restrict__ cat,
                                                   const float* __restrict__ gw2,
                                                   const float* __restrict__ gb2,
                                                   float* __restrict__ ew) {
  const int ln = threadIdx.x & 63;
  const int token = (int)((blockIdx.x * 256 + threadIdx.x) >> 6);
  const u16* row = cat + (size_t)token * 768;
  float a[8] = {0.f, 0.f, 0.f, 0.f, 0.f, 0.f, 0.f, 0.f};
#pragma unroll
  for (int kk = 0; kk < 12; ++kk) {
    const int k = kk * 64 + ln;
    const float x = bf2f(row[k]);
    const float4* wr = reinterpret_cast<const float4*>(gw2 + (size_t)k * 8);
    const float4 w0 = wr[0], w1 = wr[1];
    a[0] += x * w0.x; a[1] += x * w0.y; a[2] += x * w0.z; a[3] += x * w0.w;
    a[4] += x * w1.x; a[5] += x * w1.y; a[6] += x * w1.z; a[7] += x * w1.w;
  }
#pragma unroll
  for (int j = 0; j < 8; ++j) {
#pragma unroll
    for (int d = 32; d > 0; d >>= 1) a[j] += __shfl_xor(a[j], d);
    a[j] += gb2[j];
  }
  float mx = a[0];
#pragma unroll
  for (int j = 1; j < 8; ++j) mx = fmaxf(mx, a[j]);
  float s = 0.f, pj[8];
#pragma unroll
  for (int j = 0; j < 8; ++j) { pj[j] = expf(a[j] - mx); s += pj[j]; }
  const float inv = 1.f / s;
  if (ln == 0) {
#pragma unroll
    for (int j = 0; j < 8; ++j) ew[(size_t)token * 8 + j] = pj[j] * inv;
  }
}

// ---------------------------------------------------------------------------
// 128x128 bf16 MFMA GEMM (gating layers only; small fraction of runtime).
// ---------------------------------------------------------------------------
template <int MODE, int BK>
__global__ __launch_bounds__(256) void gemm_mfma(
    const u16* __restrict__ A, const u16* __restrict__ Bt,
    const float* __restrict__ bias, const float* __restrict__ ew,
    void* __restrict__ outp, int M, int N, int K,
    int out_stride, int out_col0) {
  constexpr int SLOTS = BK / 8;
  constexpr int SSH   = (BK == 32) ? 2 : 3;
  constexpr int CROWS = 1024 / (BK * 2);
  constexpr int LOADS = BK / 16;

  __shared__ alignas(16) u16 As[128 * BK];
  __shared__ alignas(16) u16 Bs[128 * BK];

  const int tid = threadIdx.x;
  const int ln  = tid & 63;
  const int wv  = tid >> 6;
  const int wr  = wv >> 1;
  const int wc  = wv & 1;
  const int m0  = blockIdx.y * 128;
  const int n0  = blockIdx.x * 128;

  const int lrow  = ln >> SSH;
  const int lslot = ln & (SLOTS - 1);
  const int fw    = (BK == 64) ? (lrow & 7) : ((lrow >> 1) & 3);
  const int gcol  = ((lslot ^ fw) << 3);
  const int c0    = wv * LOADS;

  const u16* gA[LOADS]; const u16* gB[LOADS];
  u16* lA[LOADS]; u16* lB[LOADS];
#pragma unroll
  for (int t = 0; t < LOADS; ++t) {
    const int rowg = (c0 + t) * CROWS + lrow;
    gA[t] = A  + (size_t)(m0 + rowg) * K + gcol;
    gB[t] = Bt + (size_t)(n0 + rowg) * K + gcol;
    lA[t] = &As[(size_t)(c0 + t) * 512];
    lB[t] = &Bs[(size_t)(c0 + t) * 512];
  }

  f32x4 acc[4][4];
#pragma unroll
  for (int i = 0; i < 4; ++i)
#pragma unroll
    for (int j = 0; j < 4; ++j) acc[i][j] = (f32x4){0.f, 0.f, 0.f, 0.f};

  const int ar  = ln & 15;
  const int hi  = ln >> 4;
  const int arf = (BK == 64) ? (ar & 7) : ((ar >> 1) & 3);

  const int kIters = K / BK;
  for (int kt = 0; kt < kIters; ++kt) {
#pragma unroll
    for (int t = 0; t < LOADS; ++t) gload16(gA[t], lA[t]);
#pragma unroll
    for (int t = 0; t < LOADS; ++t) gload16(gB[t], lB[t]);
#pragma unroll
    for (int t = 0; t < LOADS; ++t) { gA[t] += BK; gB[t] += BK; }
    __syncthreads();

#pragma unroll
    for (int k32 = 0; k32 < BK / 32; ++k32) {
      bf16x8 af[4], bfv[4];
#pragma unroll
      for (int i = 0; i < 4; ++i)
        af[i] = *reinterpret_cast<const bf16x8*>(
            &As[(size_t)(wr * 64 + i * 16 + ar) * BK + (((k32 * 4 + hi) ^ arf) << 3)]);
#pragma unroll
      for (int j = 0; j < 4; ++j)
        bfv[j] = *reinterpret_cast<const bf16x8*>(
            &Bs[(size_t)(wc * 64 + j * 16 + ar) * BK + (((k32 * 4 + hi) ^ arf) << 3)]);
#pragma unroll
      for (int i = 0; i < 4; ++i)
#pragma unroll
        for (int j = 0; j < 4; ++j)
          acc[i][j] = __builtin_amdgcn_mfma_f32_16x16x32_bf16(af[i], bfv[j], acc[i][j], 0, 0, 0);
    }
    __syncthreads();
  }

  const int m0w = m0 + wr * 64 + (ln >> 4) * 4;
  const int n0w = n0 + wc * 64 + (ln & 15);
  u16* outb = (u16*)outp;
#pragma unroll
  for (int j = 0; j < 4; ++j) {
    const int n = n0w + j * 16;
    const float bv = bias[n];
#pragma unroll
    for (int i = 0; i < 4; ++i) {
#pragma unroll
      for (int r = 0; r < 4; ++r) {
        const int m = m0w + i * 16 + r;
        outb[(size_t)m * out_stride + out_col0 + n] = f2bf(eluf(acc[i][j][r] + bv));
      }
    }
  }
}

// ---------------------------------------------------------------------------
// Expert GEMM: 256x256 tile, 8 waves (2Mx4N), BK=64, SINGLE-buffered LDS
// (64 KiB -> 2 blocks/CU; inter-block overlap covers the per-tile vmcnt(0)
// drain, the m97/m114 mechanism). 2-phase loop: stage -> sync -> 64 MFMA ->
// sync. 32 MFMA per barrier. XCD-aware block swizzle (T1).
// __launch_bounds__(512, 2): 2 waves/SIMD min -> 256-reg budget; compiler's
// ~112 VGPR allocation then permits 4 waves/SIMD = 2 blocks/CU. (R7's (512,4)
// capped regs at 128 -> acc spilled to scratch -> 1 GB/dispatch. Rule #15.)
// LDS XOR-swizzle both-sides (slot ^= row&7), linear gload_lds dest +
// pre-swizzled global source.
// MODE 1: n = dout*8+e; out = elu(sum_e ew[m,e]*(acc+bias[e*Dout+dout])), bf16.
// MODE 2: same but fp32 write, no elu (final layer).
// ---------------------------------------------------------------------------
template <int MODE>
__global__ __launch_bounds__(512, 2) void gemm256s(
    const u16* __restrict__ A, const u16* __restrict__ Bt,
    const float* __restrict__ bias, const float* __restrict__ ew,
    void* __restrict__ outp, int N, int K, int out_stride, int out_col0,
    int bxPerXcd) {
  constexpr int BK = 64;
  __shared__ alignas(16) u16 As[256 * BK];  // 32 KiB
  __shared__ alignas(16) u16 Bs[256 * BK];  // 32 KiB

  const int tid = threadIdx.x;
  const int ln  = tid & 63;
  const int wv  = tid >> 6;     // 0..7
  const int wr  = wv >> 2;      // 0..1  (M half)
  const int wc  = wv & 3;       // 0..3  (N quarter)

  // XCD-aware decode: bid&7 = XCD; each XCD owns bxPerXcd adjacent N-tiles.
  const int bid = blockIdx.x;
  const int xcd = bid & 7;
  const int s   = bid >> 3;
  const int bx  = xcd * bxPerXcd + (s % bxPerXcd);
  const int by  = s / bxPerXcd;
  const int m0  = by * 256;
  const int n0  = bx * 256;

  // staging: wave wv stages chunks wv*4+q (q=0..3); chunk = 8 rows x 64 col
  const int lrow  = ln >> 3;          // 0..7 row within chunk
  const int gslot = (ln & 7) ^ lrow;  // pre-swizzled 16B slot within row
  const u16* gA[4]; const u16* gB[4];
#pragma unroll
  for (int q = 0; q < 4; ++q) {
    const int row = (wv * 4 + q) * 8 + lrow;
    gA[q] = A  + (size_t)(m0 + row) * K + gslot * 8;
    gB[q] = Bt + (size_t)(n0 + row) * K + gslot * 8;
  }

  f32x4 acc[8][4];
#pragma unroll
  for (int i = 0; i < 8; ++i)
#pragma unroll
    for (int j = 0; j < 4; ++j) acc[i][j] = (f32x4){0.f, 0.f, 0.f, 0.f};

  const int ar  = ln & 15;
  const int hi  = ln >> 4;       // 0..3
  const int arf = ar & 7;        // read-side swizzle
  const int sl0 = (hi ^ arf) << 3;        // kk=0 u16 offset
  const int sl1 = ((4 + hi) ^ arf) << 3;  // kk=1 u16 offset

  const int nt = K / BK;

  for (int t = 0; t < nt; ++t) {
#pragma unroll
    for (int q = 0; q < 4; ++q) {
      gload16(gA[q], &As[(size_t)((wv * 4 + q) * 8) * 64]);
      gload16(gB[q], &Bs[(size_t)((wv * 4 + q) * 8) * 64]);
      gA[q] += BK; gB[q] += BK;
    }
    __syncthreads();  // drains vmcnt(0)+lgkmcnt(0): tile staged & visible

    const u16* Ab = &As[(size_t)(wr * 128 + ar) * BK];
    const u16* Bb = &Bs[(size_t)(wc * 64 + ar) * BK];
#pragma unroll
    for (int kk = 0; kk < 2; ++kk) {
      const int sl = kk ? sl1 : sl0;
      bf16x8 bv[4], av[8];
#pragma unroll
      for (int j = 0; j < 4; ++j)
        bv[j] = *reinterpret_cast<const bf16x8*>(Bb + (size_t)j * 16 * BK + sl);
#pragma unroll
      for (int i = 0; i < 8; ++i)
        av[i] = *reinterpret_cast<const bf16x8*>(Ab + (size_t)i * 16 * BK + sl);
      __builtin_amdgcn_s_setprio(1);
#pragma unroll
      for (int i = 0; i < 8; ++i)
#pragma unroll
        for (int j = 0; j < 4; ++j)
          acc[i][j] = __builtin_amdgcn_mfma_f32_16x16x32_bf16(av[i], bv[j], acc[i][j], 0, 0, 0);
      __builtin_amdgcn_s_setprio(0);
    }
    __syncthreads();  // all reads done before next stage overwrites
  }

  // Epilogue. C/D: col = lane&15, row = (lane>>4)*4 + reg.
  const int e = ln & 7;                      // expert (j-invariant)
  const int m_base = m0 + wr * 128 + hi * 4;
  const int Dout = N >> 3;
  float ewv[32];
#pragma unroll
  for (int i = 0; i < 8; ++i)
#pragma unroll
    for (int r = 0; r < 4; ++r)
      ewv[i * 4 + r] = ew[(size_t)(m_base + i * 16 + r) * 8 + e];
#pragma unroll
  for (int j = 0; j < 4; ++j) {
    const int n = n0 + wc * 64 + j * 16 + (ln & 15);
    const int dout = n >> 3;
    const float bv = bias[(size_t)e * Dout + dout];
#pragma unroll
    for (int i = 0; i < 8; ++i) {
#pragma unroll
      for (int r = 0; r < 4; ++r) {
        const int m = m_base + i * 16 + r;
        float v = (acc[i][j][r] + bv) * ewv[i * 4 + r];
        v += __shfl_xor(v, 1);
        v += __shfl_xor(v, 2);
        v += __shfl_xor(v, 4);
        if ((ln & 7) == 0) {
          if (MODE == 1) {
            ((u16*)outp)[(size_t)m * out_stride + out_col0 + dout] = f2bf(eluf(v));
          } else {
            ((float*)outp)[(size_t)m * out_stride + dout] = v;
          }
        }
      }
    }
  }
}

// ---------------------------------------------------------------------------
extern "C" void kernel_launch(void* const* d_in, const int* in_sizes, int n_in,
                              void* d_out, int out_size, void* d_ws, size_t ws_size,
                              hipStream_t stream) {
  const float* z   = (const float*)d_in[0];
  const float* p   = (const float*)d_in[1];
  const float* vh  = (const float*)d_in[2];
  const float* xc  = (const float*)d_in[3];
  const float* gw0 = (const float*)d_in[4];
  const float* gb0 = (const float*)d_in[5];
  const float* gw1 = (const float*)d_in[6];
  const float* gb1 = (const float*)d_in[7];
  const float* gw2 = (const float*)d_in[8];
  const float* gb2 = (const float*)d_in[9];
  const float* w0  = (const float*)d_in[10];
  const float* b0  = (const float*)d_in[11];
  const float* w1  = (const float*)d_in[12];
  const float* b1  = (const float*)d_in[13];
  const float* w2  = (const float*)d_in[14];
  const float* b2  = (const float*)d_in[15];
  const float* wo  = (const float*)d_in[16];
  const float* bo  = (const float*)d_in[17];
  float* out = (float*)d_out;

  char* ws = (char*)d_ws;
  size_t off = 0;
  auto alloc = [&](size_t bytes) {
    char* pp = ws + off;
    off += (bytes + 255) & ~(size_t)255;
    return pp;
  };
  u16* gw0t  = (u16*)alloc((size_t)512 * 288 * 2);
  u16* gw1t  = (u16*)alloc((size_t)512 * 768 * 2);
  u16* w0t   = (u16*)alloc((size_t)4096 * 576 * 2);
  u16* w1t   = (u16*)alloc((size_t)4096 * 768 * 2);
  u16* w2t   = (u16*)alloc((size_t)4096 * 768 * 2);
  u16* wot   = (u16*)alloc((size_t)2048 * 768 * 2);
  u16* catP  = (u16*)alloc((size_t)8192 * 288 * 2);
  u16* catE0 = (u16*)alloc((size_t)8192 * 576 * 2);
  u16* cat0  = (u16*)alloc((size_t)8192 * 768 * 2);
  u16* cat1  = (u16*)alloc((size_t)8192 * 768 * 2);
  float* ew  = (float*)alloc((size_t)8192 * 8 * 4);
  (void)ws_size; (void)in_sizes; (void)n_in; (void)out_size;

  const dim3 tb(32, 8);
  transpose_convert<<<dim3(9, 16, 1),  tb, 0, stream>>>(gw0, gw0t, 272, 512, 288, 1);
  transpose_convert<<<dim3(24, 16, 1), tb, 0, stream>>>(gw1, gw1t, 768, 512, 768, 1);
  transpose_convert<<<dim3(18, 16, 8), tb, 0, stream>>>(w0,  w0t,  515, 512, 576, 8);
  transpose_convert<<<dim3(24, 16, 8), tb, 0, stream>>>(w1,  w1t,  768, 512, 768, 8);
  transpose_convert<<<dim3(24, 16, 8), tb, 0, stream>>>(w2,  w2t,  768, 512, 768, 8);
  transpose_convert<<<dim3(24, 8, 8),  tb, 0, stream>>>(wo,  wot,  768, 256, 768, 8);
  prep_cat<<<8192, 256, 0, stream>>>(z, p, vh, xc, catP, catE0, cat0, cat1);

  // gating (small: keep proven 128^2 kernel)
  gemm_mfma<0, 32><<<dim3(4, 64), 256, 0, stream>>>(catP, gw0t, gb0, nullptr, cat0,
                                                    8192, 512, 288, 768, 256);
  gemm_mfma<0, 64><<<dim3(4, 64), 256, 0, stream>>>(cat0, gw1t, gb1, nullptr, cat1,
                                                    8192, 512, 768, 768, 256);
  gating_tail<<<2048, 256, 0, stream>>>(cat1, gw2, gb2, ew);

  // expert layers: 256^2 single-buffered (64 KiB -> 2 blocks/CU), XCD-swizzled
  gemm256s<1><<<512, 512, 0, stream>>>(catE0, w0t, b0, ew, cat0,
                                       4096, 576, 768, 256, 2);
  gemm256s<1><<<512, 512, 0, stream>>>(cat0, w1t, b1, ew, cat1,
                                       4096, 768, 768, 256, 2);
  gemm256s<1><<<512, 512, 0, stream>>>(cat1, w2t, b2, ew, cat0,
                                       4096, 768, 768, 256, 2);
  gemm256s<2><<<256, 512, 0, stream>>>(cat0, wot, bo, ew, out,
                                       2048, 768, 256, 0, 1);
}

// Round 9
// 401.400 us; speedup vs baseline: 5.3665x; 1.0832x over previous
//
#include <hip/hip_runtime.h>
#include <cstdint>
#include <cstddef>

using u16 = unsigned short;
using bf16x8 = __attribute__((ext_vector_type(8))) __bf16;
using f32x4  = __attribute__((ext_vector_type(4))) float;

static __device__ __forceinline__ u16 f2bf(float f) {
  unsigned u = __builtin_bit_cast(unsigned, f);
  unsigned r = (u + 0x7fffu + ((u >> 16) & 1u)) >> 16;  // RNE
  return (u16)r;
}
static __device__ __forceinline__ float bf2f(u16 h) {
  unsigned u = ((unsigned)h) << 16;
  return __builtin_bit_cast(float, u);
}
static __device__ __forceinline__ float eluf(float x) {
  return x > 0.f ? x : expm1f(x);
}
static __device__ __forceinline__ void gload16(const u16* g, u16* l) {
  __builtin_amdgcn_global_load_lds(
      (const __attribute__((address_space(1))) void*)g,
      (__attribute__((address_space(3))) void*)l, 16, 0, 0);
}

// ---------------------------------------------------------------------------
// Weight transpose+convert: src (E, Ksrc, Nsrc) f32  ->  dst bf16 (Nsrc*E, Kpad)
// ---------------------------------------------------------------------------
__global__ void transpose_convert(const float* __restrict__ src, u16* __restrict__ dst,
                                  int Ksrc, int Nsrc, int Kpad, int E) {
  __shared__ float tile[32][33];
  const int e  = blockIdx.z;
  const int k0 = blockIdx.x * 32;
  const int d0 = blockIdx.y * 32;
  const int tx = threadIdx.x;  // 0..31
  const int ty = threadIdx.y;  // 0..7
  const float* s = src + (size_t)e * Ksrc * Nsrc;
#pragma unroll
  for (int i = 0; i < 4; ++i) {
    const int k = k0 + ty + i * 8;
    float v = 0.f;
    if (k < Ksrc) v = s[(size_t)k * Nsrc + d0 + tx];
    tile[ty + i * 8][tx] = v;
  }
  __syncthreads();
#pragma unroll
  for (int i = 0; i < 4; ++i) {
    const int d = d0 + ty + i * 8;
    dst[((size_t)d * E + e) * Kpad + k0 + tx] = f2bf(tile[tx][ty + i * 8]);
  }
}

// ---------------------------------------------------------------------------
// Build bf16 concat buffers.
// ---------------------------------------------------------------------------
__global__ void prep_cat(const float* __restrict__ z, const float* __restrict__ p,
                         const float* __restrict__ vh, const float* __restrict__ xc,
                         u16* __restrict__ catP, u16* __restrict__ catE0,
                         u16* __restrict__ cat0, u16* __restrict__ cat1) {
  const int m = blockIdx.x;
  const int t = threadIdx.x;  // 0..255
  const u16 zb = f2bf(z[(size_t)m * 256 + t]);
  catP [(size_t)m * 288 + t] = zb;
  catE0[(size_t)m * 576 + t] = zb;
  cat0 [(size_t)m * 768 + t] = zb;
  cat1 [(size_t)m * 768 + t] = zb;
  if (t < 32) {
    const u16 val = (t < 16) ? f2bf(p[(size_t)m * 16 + t]) : (u16)0;
    catP[(size_t)m * 288 + 256 + t] = val;
  }
  for (int c = 256 + t; c < 576; c += 256) {
    const int idx = c - 256;
    float v = 0.f;
    if (idx < 3)        v = vh[(size_t)m * 3 + idx];
    else if (idx < 259) v = xc[(size_t)m * 256 + (idx - 3)];
    catE0[(size_t)m * 576 + c] = f2bf(v);
  }
}

// ---------------------------------------------------------------------------
// Gating layer 2 (N=8) + softmax: one wave per token.
// ---------------------------------------------------------------------------
__global__ __launch_bounds__(256) void gating_tail(const u16* __restrict__ cat,
                                                   const float* __restrict__ gw2,
                                                   const float* __restrict__ gb2,
                                                   float* __restrict__ ew) {
  const int ln = threadIdx.x & 63;
  const int token = (int)((blockIdx.x * 256 + threadIdx.x) >> 6);
  const u16* row = cat + (size_t)token * 768;
  float a[8] = {0.f, 0.f, 0.f, 0.f, 0.f, 0.f, 0.f, 0.f};
#pragma unroll
  for (int kk = 0; kk < 12; ++kk) {
    const int k = kk * 64 + ln;
    const float x = bf2f(row[k]);
    const float4* wr = reinterpret_cast<const float4*>(gw2 + (size_t)k * 8);
    const float4 w0 = wr[0], w1 = wr[1];
    a[0] += x * w0.x; a[1] += x * w0.y; a[2] += x * w0.z; a[3] += x * w0.w;
    a[4] += x * w1.x; a[5] += x * w1.y; a[6] += x * w1.z; a[7] += x * w1.w;
  }
#pragma unroll
  for (int j = 0; j < 8; ++j) {
#pragma unroll
    for (int d = 32; d > 0; d >>= 1) a[j] += __shfl_xor(a[j], d);
    a[j] += gb2[j];
  }
  float mx = a[0];
#pragma unroll
  for (int j = 1; j < 8; ++j) mx = fmaxf(mx, a[j]);
  float s = 0.f, pj[8];
#pragma unroll
  for (int j = 0; j < 8; ++j) { pj[j] = expf(a[j] - mx); s += pj[j]; }
  const float inv = 1.f / s;
  if (ln == 0) {
#pragma unroll
    for (int j = 0; j < 8; ++j) ew[(size_t)token * 8 + j] = pj[j] * inv;
  }
}

// ---------------------------------------------------------------------------
// 128x128 bf16 MFMA GEMM (gating layers only; small fraction of runtime).
// ---------------------------------------------------------------------------
template <int MODE, int BK>
__global__ __launch_bounds__(256) void gemm_mfma(
    const u16* __restrict__ A, const u16* __restrict__ Bt,
    const float* __restrict__ bias, const float* __restrict__ ew,
    void* __restrict__ outp, int M, int N, int K,
    int out_stride, int out_col0) {
  constexpr int SLOTS = BK / 8;
  constexpr int SSH   = (BK == 32) ? 2 : 3;
  constexpr int CROWS = 1024 / (BK * 2);
  constexpr int LOADS = BK / 16;

  __shared__ alignas(16) u16 As[128 * BK];
  __shared__ alignas(16) u16 Bs[128 * BK];

  const int tid = threadIdx.x;
  const int ln  = tid & 63;
  const int wv  = tid >> 6;
  const int wr  = wv >> 1;
  const int wc  = wv & 1;
  const int m0  = blockIdx.y * 128;
  const int n0  = blockIdx.x * 128;

  const int lrow  = ln >> SSH;
  const int lslot = ln & (SLOTS - 1);
  const int fw    = (BK == 64) ? (lrow & 7) : ((lrow >> 1) & 3);
  const int gcol  = ((lslot ^ fw) << 3);
  const int c0    = wv * LOADS;

  const u16* gA[LOADS]; const u16* gB[LOADS];
  u16* lA[LOADS]; u16* lB[LOADS];
#pragma unroll
  for (int t = 0; t < LOADS; ++t) {
    const int rowg = (c0 + t) * CROWS + lrow;
    gA[t] = A  + (size_t)(m0 + rowg) * K + gcol;
    gB[t] = Bt + (size_t)(n0 + rowg) * K + gcol;
    lA[t] = &As[(size_t)(c0 + t) * 512];
    lB[t] = &Bs[(size_t)(c0 + t) * 512];
  }

  f32x4 acc[4][4];
#pragma unroll
  for (int i = 0; i < 4; ++i)
#pragma unroll
    for (int j = 0; j < 4; ++j) acc[i][j] = (f32x4){0.f, 0.f, 0.f, 0.f};

  const int ar  = ln & 15;
  const int hi  = ln >> 4;
  const int arf = (BK == 64) ? (ar & 7) : ((ar >> 1) & 3);

  const int kIters = K / BK;
  for (int kt = 0; kt < kIters; ++kt) {
#pragma unroll
    for (int t = 0; t < LOADS; ++t) gload16(gA[t], lA[t]);
#pragma unroll
    for (int t = 0; t < LOADS; ++t) gload16(gB[t], lB[t]);
#pragma unroll
    for (int t = 0; t < LOADS; ++t) { gA[t] += BK; gB[t] += BK; }
    __syncthreads();

#pragma unroll
    for (int k32 = 0; k32 < BK / 32; ++k32) {
      bf16x8 af[4], bfv[4];
#pragma unroll
      for (int i = 0; i < 4; ++i)
        af[i] = *reinterpret_cast<const bf16x8*>(
            &As[(size_t)(wr * 64 + i * 16 + ar) * BK + (((k32 * 4 + hi) ^ arf) << 3)]);
#pragma unroll
      for (int j = 0; j < 4; ++j)
        bfv[j] = *reinterpret_cast<const bf16x8*>(
            &Bs[(size_t)(wc * 64 + j * 16 + ar) * BK + (((k32 * 4 + hi) ^ arf) << 3)]);
#pragma unroll
      for (int i = 0; i < 4; ++i)
#pragma unroll
        for (int j = 0; j < 4; ++j)
          acc[i][j] = __builtin_amdgcn_mfma_f32_16x16x32_bf16(af[i], bfv[j], acc[i][j], 0, 0, 0);
    }
    __syncthreads();
  }

  const int m0w = m0 + wr * 64 + (ln >> 4) * 4;
  const int n0w = n0 + wc * 64 + (ln & 15);
  u16* outb = (u16*)outp;
#pragma unroll
  for (int j = 0; j < 4; ++j) {
    const int n = n0w + j * 16;
    const float bv = bias[n];
#pragma unroll
    for (int i = 0; i < 4; ++i) {
#pragma unroll
      for (int r = 0; r < 4; ++r) {
        const int m = m0w + i * 16 + r;
        outb[(size_t)m * out_stride + out_col0 + n] = f2bf(eluf(acc[i][j][r] + bv));
      }
    }
  }
}

// ---------------------------------------------------------------------------
// Expert GEMM, m97-exact residency structure: 128x128 tile, 4 waves, BK=64,
// SINGLE-buffered 32 KiB LDS, 2-phase loop (stage -> sync -> 32 MFMA/barrier
// -> sync). Key: total regs/wave = ~100 arch + 64 acc(AGPR) = ~164 ->
// __launch_bounds__(256,3) pins 3 waves/SIMD -> 3 BLOCKS/CU co-resident.
// Inter-block overlap (m114) covers each block's stage/drain/epilogue — the
// mechanism every 1-resident 256^2 variant (R3-R8, 240 regs/wave) lacked.
// Grid linear (bx fast over N): 32 consecutive blocks share one A-panel ->
// L2 broadcast.
// LDS XOR-swizzle both-sides (slot ^= row&7), linear gload_lds dest +
// pre-swizzled global source.
// MODE 1: n = dout*8+e; out = elu(sum_e ew[m,e]*(acc+bias[e*Dout+dout])), bf16.
// MODE 2: same but fp32 write, no elu (final layer).
// ---------------------------------------------------------------------------
template <int MODE>
__global__ __launch_bounds__(256, 3) void gemm128e(
    const u16* __restrict__ A, const u16* __restrict__ Bt,
    const float* __restrict__ bias, const float* __restrict__ ew,
    void* __restrict__ outp, int N, int K, int out_stride, int out_col0) {
  constexpr int BK = 64;
  __shared__ alignas(16) u16 As[128 * BK];  // 16 KiB
  __shared__ alignas(16) u16 Bs[128 * BK];  // 16 KiB

  const int tid = threadIdx.x;
  const int ln  = tid & 63;
  const int wv  = tid >> 6;       // 0..3
  const int wr  = wv >> 1;        // M half
  const int wc  = wv & 1;         // N half
  const int m0  = blockIdx.y * 128;
  const int n0  = blockIdx.x * 128;

  // staging: chunk = 8 rows x 64 cols = 1 KB/wave-instr; wave wv covers rows
  // [wv*32, wv*32+32) of A and of B -> 4 gloads each.
  const int lrow  = ln >> 3;          // 0..7 row within chunk
  const int gslot = (ln & 7) ^ lrow;  // pre-swizzled 16B slot within row
  const u16* gA[4]; const u16* gB[4];
#pragma unroll
  for (int q = 0; q < 4; ++q) {
    const int row = wv * 32 + q * 8 + lrow;
    gA[q] = A  + (size_t)(m0 + row) * K + gslot * 8;
    gB[q] = Bt + (size_t)(n0 + row) * K + gslot * 8;
  }

  f32x4 acc[4][4];
#pragma unroll
  for (int i = 0; i < 4; ++i)
#pragma unroll
    for (int j = 0; j < 4; ++j) acc[i][j] = (f32x4){0.f, 0.f, 0.f, 0.f};

  const int ar  = ln & 15;
  const int hi  = ln >> 4;       // 0..3
  const int arf = ar & 7;        // read-side swizzle
  const int sl0 = (hi ^ arf) << 3;        // kk=0 u16 offset
  const int sl1 = ((4 + hi) ^ arf) << 3;  // kk=1 u16 offset

  const int nt = K / BK;

  for (int t = 0; t < nt; ++t) {
#pragma unroll
    for (int q = 0; q < 4; ++q) {
      gload16(gA[q], &As[(size_t)(wv * 32 + q * 8) * 64]);
      gload16(gB[q], &Bs[(size_t)(wv * 32 + q * 8) * 64]);
      gA[q] += BK; gB[q] += BK;
    }
    __syncthreads();  // drains vmcnt(0): tile staged & visible

    const u16* Ab = &As[(size_t)(wr * 64 + ar) * BK];
    const u16* Bb = &Bs[(size_t)(wc * 64 + ar) * BK];
#pragma unroll
    for (int kk = 0; kk < 2; ++kk) {
      const int sl = kk ? sl1 : sl0;
      bf16x8 av[4], bv[4];
#pragma unroll
      for (int i = 0; i < 4; ++i)
        av[i] = *reinterpret_cast<const bf16x8*>(Ab + (size_t)i * 16 * BK + sl);
#pragma unroll
      for (int j = 0; j < 4; ++j)
        bv[j] = *reinterpret_cast<const bf16x8*>(Bb + (size_t)j * 16 * BK + sl);
      __builtin_amdgcn_s_setprio(1);
#pragma unroll
      for (int i = 0; i < 4; ++i)
#pragma unroll
        for (int j = 0; j < 4; ++j)
          acc[i][j] = __builtin_amdgcn_mfma_f32_16x16x32_bf16(av[i], bv[j], acc[i][j], 0, 0, 0);
      __builtin_amdgcn_s_setprio(0);
    }
    __syncthreads();  // all reads done before next stage overwrites
  }

  // Epilogue. C/D: col = lane&15, row = (lane>>4)*4 + reg.
  const int e = ln & 7;               // j-invariant expert index
  const int m0w = m0 + wr * 64 + hi * 4;
  const int n0w = n0 + wc * 64 + (ln & 15);
  const int Dout = N >> 3;
  float ewv[16];
#pragma unroll
  for (int i = 0; i < 4; ++i)
#pragma unroll
    for (int r = 0; r < 4; ++r)
      ewv[i * 4 + r] = ew[(size_t)(m0w + i * 16 + r) * 8 + e];
#pragma unroll
  for (int j = 0; j < 4; ++j) {
    const int n = n0w + j * 16;
    const int dout = n >> 3;
    const float bv = bias[(size_t)e * Dout + dout];
#pragma unroll
    for (int i = 0; i < 4; ++i) {
#pragma unroll
      for (int r = 0; r < 4; ++r) {
        const int m = m0w + i * 16 + r;
        float v = (acc[i][j][r] + bv) * ewv[i * 4 + r];
        v += __shfl_xor(v, 1);
        v += __shfl_xor(v, 2);
        v += __shfl_xor(v, 4);
        if ((ln & 7) == 0) {
          if (MODE == 1) {
            ((u16*)outp)[(size_t)m * out_stride + out_col0 + dout] = f2bf(eluf(v));
          } else {
            ((float*)outp)[(size_t)m * out_stride + dout] = v;
          }
        }
      }
    }
  }
}

// ---------------------------------------------------------------------------
extern "C" void kernel_launch(void* const* d_in, const int* in_sizes, int n_in,
                              void* d_out, int out_size, void* d_ws, size_t ws_size,
                              hipStream_t stream) {
  const float* z   = (const float*)d_in[0];
  const float* p   = (const float*)d_in[1];
  const float* vh  = (const float*)d_in[2];
  const float* xc  = (const float*)d_in[3];
  const float* gw0 = (const float*)d_in[4];
  const float* gb0 = (const float*)d_in[5];
  const float* gw1 = (const float*)d_in[6];
  const float* gb1 = (const float*)d_in[7];
  const float* gw2 = (const float*)d_in[8];
  const float* gb2 = (const float*)d_in[9];
  const float* w0  = (const float*)d_in[10];
  const float* b0  = (const float*)d_in[11];
  const float* w1  = (const float*)d_in[12];
  const float* b1  = (const float*)d_in[13];
  const float* w2  = (const float*)d_in[14];
  const float* b2  = (const float*)d_in[15];
  const float* wo  = (const float*)d_in[16];
  const float* bo  = (const float*)d_in[17];
  float* out = (float*)d_out;

  char* ws = (char*)d_ws;
  size_t off = 0;
  auto alloc = [&](size_t bytes) {
    char* pp = ws + off;
    off += (bytes + 255) & ~(size_t)255;
    return pp;
  };
  u16* gw0t  = (u16*)alloc((size_t)512 * 288 * 2);
  u16* gw1t  = (u16*)alloc((size_t)512 * 768 * 2);
  u16* w0t   = (u16*)alloc((size_t)4096 * 576 * 2);
  u16* w1t   = (u16*)alloc((size_t)4096 * 768 * 2);
  u16* w2t   = (u16*)alloc((size_t)4096 * 768 * 2);
  u16* wot   = (u16*)alloc((size_t)2048 * 768 * 2);
  u16* catP  = (u16*)alloc((size_t)8192 * 288 * 2);
  u16* catE0 = (u16*)alloc((size_t)8192 * 576 * 2);
  u16* cat0  = (u16*)alloc((size_t)8192 * 768 * 2);
  u16* cat1  = (u16*)alloc((size_t)8192 * 768 * 2);
  float* ew  = (float*)alloc((size_t)8192 * 8 * 4);
  (void)ws_size; (void)in_sizes; (void)n_in; (void)out_size;

  const dim3 tb(32, 8);
  transpose_convert<<<dim3(9, 16, 1),  tb, 0, stream>>>(gw0, gw0t, 272, 512, 288, 1);
  transpose_convert<<<dim3(24, 16, 1), tb, 0, stream>>>(gw1, gw1t, 768, 512, 768, 1);
  transpose_convert<<<dim3(18, 16, 8), tb, 0, stream>>>(w0,  w0t,  515, 512, 576, 8);
  transpose_convert<<<dim3(24, 16, 8), tb, 0, stream>>>(w1,  w1t,  768, 512, 768, 8);
  transpose_convert<<<dim3(24, 16, 8), tb, 0, stream>>>(w2,  w2t,  768, 512, 768, 8);
  transpose_convert<<<dim3(24, 8, 8),  tb, 0, stream>>>(wo,  wot,  768, 256, 768, 8);
  prep_cat<<<8192, 256, 0, stream>>>(z, p, vh, xc, catP, catE0, cat0, cat1);

  // gating (small: keep proven 128^2 kernel)
  gemm_mfma<0, 32><<<dim3(4, 64), 256, 0, stream>>>(catP, gw0t, gb0, nullptr, cat0,
                                                    8192, 512, 288, 768, 256);
  gemm_mfma<0, 64><<<dim3(4, 64), 256, 0, stream>>>(cat0, gw1t, gb1, nullptr, cat1,
                                                    8192, 512, 768, 768, 256);
  gating_tail<<<2048, 256, 0, stream>>>(cat1, gw2, gb2, ew);

  // expert layers: 128^2 BK=64 single-buffer, 3 blocks/CU co-resident
  gemm128e<1><<<dim3(32, 64), 256, 0, stream>>>(catE0, w0t, b0, ew, cat0,
                                                4096, 576, 768, 256);
  gemm128e<1><<<dim3(32, 64), 256, 0, stream>>>(cat0, w1t, b1, ew, cat1,
                                                4096, 768, 768, 256);
  gemm128e<1><<<dim3(32, 64), 256, 0, stream>>>(cat1, w2t, b2, ew, cat0,
                                                4096, 768, 768, 256);
  gemm128e<2><<<dim3(16, 64), 256, 0, stream>>>(cat0, wot, bo, ew, out,
                                                2048, 768, 256, 0);
}

// Round 10
// 291.300 us; speedup vs baseline: 7.3948x; 1.3780x over previous
//
#include <hip/hip_runtime.h>
#include <cstdint>
#include <cstddef>

using u16 = unsigned short;
using bf16x8 = __attribute__((ext_vector_type(8))) __bf16;
using f32x4  = __attribute__((ext_vector_type(4))) float;

static __device__ __forceinline__ u16 f2bf(float f) {
  unsigned u = __builtin_bit_cast(unsigned, f);
  unsigned r = (u + 0x7fffu + ((u >> 16) & 1u)) >> 16;  // RNE
  return (u16)r;
}
static __device__ __forceinline__ float bf2f(u16 h) {
  unsigned u = ((unsigned)h) << 16;
  return __builtin_bit_cast(float, u);
}
static __device__ __forceinline__ float eluf(float x) {
  return x > 0.f ? x : expm1f(x);
}
static __device__ __forceinline__ void gload16(const u16* g, u16* l) {
  __builtin_amdgcn_global_load_lds(
      (const __attribute__((address_space(1))) void*)g,
      (__attribute__((address_space(3))) void*)l, 16, 0, 0);
}

// ---------------------------------------------------------------------------
// Weight transpose+convert: src (E, Ksrc, Nsrc) f32  ->  dst bf16 (Nsrc*E, Kpad)
// ---------------------------------------------------------------------------
__global__ void transpose_convert(const float* __restrict__ src, u16* __restrict__ dst,
                                  int Ksrc, int Nsrc, int Kpad, int E) {
  __shared__ float tile[32][33];
  const int e  = blockIdx.z;
  const int k0 = blockIdx.x * 32;
  const int d0 = blockIdx.y * 32;
  const int tx = threadIdx.x;  // 0..31
  const int ty = threadIdx.y;  // 0..7
  const float* s = src + (size_t)e * Ksrc * Nsrc;
#pragma unroll
  for (int i = 0; i < 4; ++i) {
    const int k = k0 + ty + i * 8;
    float v = 0.f;
    if (k < Ksrc) v = s[(size_t)k * Nsrc + d0 + tx];
    tile[ty + i * 8][tx] = v;
  }
  __syncthreads();
#pragma unroll
  for (int i = 0; i < 4; ++i) {
    const int d = d0 + ty + i * 8;
    dst[((size_t)d * E + e) * Kpad + k0 + tx] = f2bf(tile[tx][ty + i * 8]);
  }
}

// ---------------------------------------------------------------------------
// Build bf16 concat buffers.
// ---------------------------------------------------------------------------
__global__ void prep_cat(const float* __restrict__ z, const float* __restrict__ p,
                         const float* __restrict__ vh, const float* __restrict__ xc,
                         u16* __restrict__ catP, u16* __restrict__ catE0,
                         u16* __restrict__ cat0, u16* __restrict__ cat1) {
  const int m = blockIdx.x;
  const int t = threadIdx.x;  // 0..255
  const u16 zb = f2bf(z[(size_t)m * 256 + t]);
  catP [(size_t)m * 288 + t] = zb;
  catE0[(size_t)m * 576 + t] = zb;
  cat0 [(size_t)m * 768 + t] = zb;
  cat1 [(size_t)m * 768 + t] = zb;
  if (t < 32) {
    const u16 val = (t < 16) ? f2bf(p[(size_t)m * 16 + t]) : (u16)0;
    catP[(size_t)m * 288 + 256 + t] = val;
  }
  for (int c = 256 + t; c < 576; c += 256) {
    const int idx = c - 256;
    float v = 0.f;
    if (idx < 3)        v = vh[(size_t)m * 3 + idx];
    else if (idx < 259) v = xc[(size_t)m * 256 + (idx - 3)];
    catE0[(size_t)m * 576 + c] = f2bf(v);
  }
}

// ---------------------------------------------------------------------------
// Gating layer 2 (N=8) + softmax: one wave per token.
// ---------------------------------------------------------------------------
__global__ __launch_bounds__(256) void gating_tail(const u16* __restrict__ cat,
                                                   const float* __restrict__ gw2,
                                                   const float* __restrict__ gb2,
                                                   float* __restrict__ ew) {
  const int ln = threadIdx.x & 63;
  const int token = (int)((blockIdx.x * 256 + threadIdx.x) >> 6);
  const u16* row = cat + (size_t)token * 768;
  float a[8] = {0.f, 0.f, 0.f, 0.f, 0.f, 0.f, 0.f, 0.f};
#pragma unroll
  for (int kk = 0; kk < 12; ++kk) {
    const int k = kk * 64 + ln;
    const float x = bf2f(row[k]);
    const float4* wr = reinterpret_cast<const float4*>(gw2 + (size_t)k * 8);
    const float4 w0 = wr[0], w1 = wr[1];
    a[0] += x * w0.x; a[1] += x * w0.y; a[2] += x * w0.z; a[3] += x * w0.w;
    a[4] += x * w1.x; a[5] += x * w1.y; a[6] += x * w1.z; a[7] += x * w1.w;
  }
#pragma unroll
  for (int j = 0; j < 8; ++j) {
#pragma unroll
    for (int d = 32; d > 0; d >>= 1) a[j] += __shfl_xor(a[j], d);
    a[j] += gb2[j];
  }
  float mx = a[0];
#pragma unroll
  for (int j = 1; j < 8; ++j) mx = fmaxf(mx, a[j]);
  float s = 0.f, pj[8];
#pragma unroll
  for (int j = 0; j < 8; ++j) { pj[j] = expf(a[j] - mx); s += pj[j]; }
  const float inv = 1.f / s;
  if (ln == 0) {
#pragma unroll
    for (int j = 0; j < 8; ++j) ew[(size_t)token * 8 + j] = pj[j] * inv;
  }
}

// ---------------------------------------------------------------------------
// 128x128 bf16 MFMA GEMM (gating layers only; small fraction of runtime).
// ---------------------------------------------------------------------------
template <int MODE, int BK>
__global__ __launch_bounds__(256) void gemm_mfma(
    const u16* __restrict__ A, const u16* __restrict__ Bt,
    const float* __restrict__ bias, const float* __restrict__ ew,
    void* __restrict__ outp, int M, int N, int K,
    int out_stride, int out_col0) {
  constexpr int SLOTS = BK / 8;
  constexpr int SSH   = (BK == 32) ? 2 : 3;
  constexpr int CROWS = 1024 / (BK * 2);
  constexpr int LOADS = BK / 16;

  __shared__ alignas(16) u16 As[128 * BK];
  __shared__ alignas(16) u16 Bs[128 * BK];

  const int tid = threadIdx.x;
  const int ln  = tid & 63;
  const int wv  = tid >> 6;
  const int wr  = wv >> 1;
  const int wc  = wv & 1;
  const int m0  = blockIdx.y * 128;
  const int n0  = blockIdx.x * 128;

  const int lrow  = ln >> SSH;
  const int lslot = ln & (SLOTS - 1);
  const int fw    = (BK == 64) ? (lrow & 7) : ((lrow >> 1) & 3);
  const int gcol  = ((lslot ^ fw) << 3);
  const int c0    = wv * LOADS;

  const u16* gA[LOADS]; const u16* gB[LOADS];
  u16* lA[LOADS]; u16* lB[LOADS];
#pragma unroll
  for (int t = 0; t < LOADS; ++t) {
    const int rowg = (c0 + t) * CROWS + lrow;
    gA[t] = A  + (size_t)(m0 + rowg) * K + gcol;
    gB[t] = Bt + (size_t)(n0 + rowg) * K + gcol;
    lA[t] = &As[(size_t)(c0 + t) * 512];
    lB[t] = &Bs[(size_t)(c0 + t) * 512];
  }

  f32x4 acc[4][4];
#pragma unroll
  for (int i = 0; i < 4; ++i)
#pragma unroll
    for (int j = 0; j < 4; ++j) acc[i][j] = (f32x4){0.f, 0.f, 0.f, 0.f};

  const int ar  = ln & 15;
  const int hi  = ln >> 4;
  const int arf = (BK == 64) ? (ar & 7) : ((ar >> 1) & 3);

  const int kIters = K / BK;
  for (int kt = 0; kt < kIters; ++kt) {
#pragma unroll
    for (int t = 0; t < LOADS; ++t) gload16(gA[t], lA[t]);
#pragma unroll
    for (int t = 0; t < LOADS; ++t) gload16(gB[t], lB[t]);
#pragma unroll
    for (int t = 0; t < LOADS; ++t) { gA[t] += BK; gB[t] += BK; }
    __syncthreads();

#pragma unroll
    for (int k32 = 0; k32 < BK / 32; ++k32) {
      bf16x8 af[4], bfv[4];
#pragma unroll
      for (int i = 0; i < 4; ++i)
        af[i] = *reinterpret_cast<const bf16x8*>(
            &As[(size_t)(wr * 64 + i * 16 + ar) * BK + (((k32 * 4 + hi) ^ arf) << 3)]);
#pragma unroll
      for (int j = 0; j < 4; ++j)
        bfv[j] = *reinterpret_cast<const bf16x8*>(
            &Bs[(size_t)(wc * 64 + j * 16 + ar) * BK + (((k32 * 4 + hi) ^ arf) << 3)]);
#pragma unroll
      for (int i = 0; i < 4; ++i)
#pragma unroll
        for (int j = 0; j < 4; ++j)
          acc[i][j] = __builtin_amdgcn_mfma_f32_16x16x32_bf16(af[i], bfv[j], acc[i][j], 0, 0, 0);
    }
    __syncthreads();
  }

  const int m0w = m0 + wr * 64 + (ln >> 4) * 4;
  const int n0w = n0 + wc * 64 + (ln & 15);
  u16* outb = (u16*)outp;
#pragma unroll
  for (int j = 0; j < 4; ++j) {
    const int n = n0w + j * 16;
    const float bv = bias[n];
#pragma unroll
    for (int i = 0; i < 4; ++i) {
#pragma unroll
      for (int r = 0; r < 4; ++r) {
        const int m = m0w + i * 16 + r;
        outb[(size_t)m * out_stride + out_col0 + n] = f2bf(eluf(acc[i][j][r] + bv));
      }
    }
  }
}

// ---------------------------------------------------------------------------
// Expert GEMM, R9 structure (128x128, 4 waves, BK=64, single-buffer 32 KiB,
// 3 blocks/CU) + TRANSPOSED-OUTPUT epilogue: main loop computes
// acc[i][j] = mfma(bv[i], av[j], .) = D[n, m] (operand swap; values and
// accumulation order identical to R9 -> bitwise-same output).
// D layout: n_row = n0 + wc*64 + i*16 + hi*4 + r, m_col = m0 + wr*64 + j*16
// + (ln&15). Since n = dout*8 + e: e = (hi&1)*4 + r (register-local!),
// dout = ((n0 + wc*64 + i*16)>>3) + (hi>>1). Expert reduction per fragment:
// 4 reg-local FMAs + ONE shfl_xor(16) + 1 add (was 3 shfl per 4 accs:
// 192 -> 16 shfl/wave, elu only on final sums).
// MODE 1: bf16 write + elu. MODE 2: fp32 write, no elu (final layer).
// ---------------------------------------------------------------------------
template <int MODE>
__global__ __launch_bounds__(256, 3) void gemm128e(
    const u16* __restrict__ A, const u16* __restrict__ Bt,
    const float* __restrict__ bias, const float* __restrict__ ew,
    void* __restrict__ outp, int N, int K, int out_stride, int out_col0) {
  constexpr int BK = 64;
  __shared__ alignas(16) u16 As[128 * BK];  // 16 KiB
  __shared__ alignas(16) u16 Bs[128 * BK];  // 16 KiB

  const int tid = threadIdx.x;
  const int ln  = tid & 63;
  const int wv  = tid >> 6;       // 0..3
  const int wr  = wv >> 1;        // M half
  const int wc  = wv & 1;         // N half
  const int m0  = blockIdx.y * 128;
  const int n0  = blockIdx.x * 128;

  // staging: chunk = 8 rows x 64 cols = 1 KB/wave-instr; wave wv covers rows
  // [wv*32, wv*32+32) of A and of B -> 4 gloads each.
  const int lrow  = ln >> 3;          // 0..7 row within chunk
  const int gslot = (ln & 7) ^ lrow;  // pre-swizzled 16B slot within row
  const u16* gA[4]; const u16* gB[4];
#pragma unroll
  for (int q = 0; q < 4; ++q) {
    const int row = wv * 32 + q * 8 + lrow;
    gA[q] = A  + (size_t)(m0 + row) * K + gslot * 8;
    gB[q] = Bt + (size_t)(n0 + row) * K + gslot * 8;
  }

  f32x4 acc[4][4];
#pragma unroll
  for (int i = 0; i < 4; ++i)
#pragma unroll
    for (int j = 0; j < 4; ++j) acc[i][j] = (f32x4){0.f, 0.f, 0.f, 0.f};

  const int ar  = ln & 15;
  const int hi  = ln >> 4;       // 0..3
  const int arf = ar & 7;        // read-side swizzle
  const int sl0 = (hi ^ arf) << 3;        // kk=0 u16 offset
  const int sl1 = ((4 + hi) ^ arf) << 3;  // kk=1 u16 offset

  const int nt = K / BK;

  for (int t = 0; t < nt; ++t) {
#pragma unroll
    for (int q = 0; q < 4; ++q) {
      gload16(gA[q], &As[(size_t)(wv * 32 + q * 8) * 64]);
      gload16(gB[q], &Bs[(size_t)(wv * 32 + q * 8) * 64]);
      gA[q] += BK; gB[q] += BK;
    }
    __syncthreads();  // drains vmcnt(0): tile staged & visible

    const u16* Ab = &As[(size_t)(wr * 64 + ar) * BK];
    const u16* Bb = &Bs[(size_t)(wc * 64 + ar) * BK];
#pragma unroll
    for (int kk = 0; kk < 2; ++kk) {
      const int sl = kk ? sl1 : sl0;
      bf16x8 av[4], bv[4];
#pragma unroll
      for (int i = 0; i < 4; ++i)
        av[i] = *reinterpret_cast<const bf16x8*>(Ab + (size_t)i * 16 * BK + sl);
#pragma unroll
      for (int j = 0; j < 4; ++j)
        bv[j] = *reinterpret_cast<const bf16x8*>(Bb + (size_t)j * 16 * BK + sl);
      __builtin_amdgcn_s_setprio(1);
#pragma unroll
      for (int i = 0; i < 4; ++i)
#pragma unroll
        for (int j = 0; j < 4; ++j)
          acc[i][j] = __builtin_amdgcn_mfma_f32_16x16x32_bf16(bv[i], av[j], acc[i][j], 0, 0, 0);
      __builtin_amdgcn_s_setprio(0);
    }
    __syncthreads();  // all reads done before next stage overwrites
  }

  // Transposed epilogue. acc[i][j] = D[n, m]:
  //   n = n0 + wc*64 + i*16 + hi*4 + r  ->  e = (hi&1)*4 + r,
  //                                         dout = nbase_i>>3 + (hi>>1)
  //   m = m0 + wr*64 + j*16 + (ln&15)
  const int lm = ln & 15;
  const int e0 = (hi & 1) * 4;
  const int dhalf = hi >> 1;
  const int Dout = N >> 3;

  float ewv[4][4];   // [j][r] = ew[m(j), e0+r]
#pragma unroll
  for (int j = 0; j < 4; ++j) {
    const int m = m0 + wr * 64 + j * 16 + lm;
#pragma unroll
    for (int r = 0; r < 4; ++r) ewv[j][r] = ew[(size_t)m * 8 + e0 + r];
  }
  float bs[4][4];    // [i][r] = bias[(e0+r)*Dout + dout(i)]
#pragma unroll
  for (int i = 0; i < 4; ++i) {
    const int di = ((n0 + wc * 64 + i * 16) >> 3) + dhalf;
#pragma unroll
    for (int r = 0; r < 4; ++r) bs[i][r] = bias[(size_t)(e0 + r) * Dout + di];
  }

#pragma unroll
  for (int i = 0; i < 4; ++i) {
    const int di = ((n0 + wc * 64 + i * 16) >> 3) + dhalf;
#pragma unroll
    for (int j = 0; j < 4; ++j) {
      float s = 0.f;
#pragma unroll
      for (int r = 0; r < 4; ++r)
        s += (acc[i][j][r] + bs[i][r]) * ewv[j][r];
      s += __shfl_xor(s, 16);   // combine e0-3 with e4-7 (hi pair)
      if ((hi & 1) == 0) {
        const int m = m0 + wr * 64 + j * 16 + lm;
        if (MODE == 1) {
          ((u16*)outp)[(size_t)m * out_stride + out_col0 + di] = f2bf(eluf(s));
        } else {
          ((float*)outp)[(size_t)m * out_stride + di] = s;
        }
      }
    }
  }
}

// ---------------------------------------------------------------------------
extern "C" void kernel_launch(void* const* d_in, const int* in_sizes, int n_in,
                              void* d_out, int out_size, void* d_ws, size_t ws_size,
                              hipStream_t stream) {
  const float* z   = (const float*)d_in[0];
  const float* p   = (const float*)d_in[1];
  const float* vh  = (const float*)d_in[2];
  const float* xc  = (const float*)d_in[3];
  const float* gw0 = (const float*)d_in[4];
  const float* gb0 = (const float*)d_in[5];
  const float* gw1 = (const float*)d_in[6];
  const float* gb1 = (const float*)d_in[7];
  const float* gw2 = (const float*)d_in[8];
  const float* gb2 = (const float*)d_in[9];
  const float* w0  = (const float*)d_in[10];
  const float* b0  = (const float*)d_in[11];
  const float* w1  = (const float*)d_in[12];
  const float* b1  = (const float*)d_in[13];
  const float* w2  = (const float*)d_in[14];
  const float* b2  = (const float*)d_in[15];
  const float* wo  = (const float*)d_in[16];
  const float* bo  = (const float*)d_in[17];
  float* out = (float*)d_out;

  char* ws = (char*)d_ws;
  size_t off = 0;
  auto alloc = [&](size_t bytes) {
    char* pp = ws + off;
    off += (bytes + 255) & ~(size_t)255;
    return pp;
  };
  u16* gw0t  = (u16*)alloc((size_t)512 * 288 * 2);
  u16* gw1t  = (u16*)alloc((size_t)512 * 768 * 2);
  u16* w0t   = (u16*)alloc((size_t)4096 * 576 * 2);
  u16* w1t   = (u16*)alloc((size_t)4096 * 768 * 2);
  u16* w2t   = (u16*)alloc((size_t)4096 * 768 * 2);
  u16* wot   = (u16*)alloc((size_t)2048 * 768 * 2);
  u16* catP  = (u16*)alloc((size_t)8192 * 288 * 2);
  u16* catE0 = (u16*)alloc((size_t)8192 * 576 * 2);
  u16* cat0  = (u16*)alloc((size_t)8192 * 768 * 2);
  u16* cat1  = (u16*)alloc((size_t)8192 * 768 * 2);
  float* ew  = (float*)alloc((size_t)8192 * 8 * 4);
  (void)ws_size; (void)in_sizes; (void)n_in; (void)out_size;

  const dim3 tb(32, 8);
  transpose_convert<<<dim3(9, 16, 1),  tb, 0, stream>>>(gw0, gw0t, 272, 512, 288, 1);
  transpose_convert<<<dim3(24, 16, 1), tb, 0, stream>>>(gw1, gw1t, 768, 512, 768, 1);
  transpose_convert<<<dim3(18, 16, 8), tb, 0, stream>>>(w0,  w0t,  515, 512, 576, 8);
  transpose_convert<<<dim3(24, 16, 8), tb, 0, stream>>>(w1,  w1t,  768, 512, 768, 8);
  transpose_convert<<<dim3(24, 16, 8), tb, 0, stream>>>(w2,  w2t,  768, 512, 768, 8);
  transpose_convert<<<dim3(24, 8, 8),  tb, 0, stream>>>(wo,  wot,  768, 256, 768, 8);
  prep_cat<<<8192, 256, 0, stream>>>(z, p, vh, xc, catP, catE0, cat0, cat1);

  // gating (small: keep proven 128^2 kernel)
  gemm_mfma<0, 32><<<dim3(4, 64), 256, 0, stream>>>(catP, gw0t, gb0, nullptr, cat0,
                                                    8192, 512, 288, 768, 256);
  gemm_mfma<0, 64><<<dim3(4, 64), 256, 0, stream>>>(cat0, gw1t, gb1, nullptr, cat1,
                                                    8192, 512, 768, 768, 256);
  gating_tail<<<2048, 256, 0, stream>>>(cat1, gw2, gb2, ew);

  // expert layers: 128^2 BK=64 single-buffer, 3 blocks/CU, transposed epilogue
  gemm128e<1><<<dim3(32, 64), 256, 0, stream>>>(catE0, w0t, b0, ew, cat0,
                                                4096, 576, 768, 256);
  gemm128e<1><<<dim3(32, 64), 256, 0, stream>>>(cat0, w1t, b1, ew, cat1,
                                                4096, 768, 768, 256);
  gemm128e<1><<<dim3(32, 64), 256, 0, stream>>>(cat1, w2t, b2, ew, cat0,
                                                4096, 768, 768, 256);
  gemm128e<2><<<dim3(16, 64), 256, 0, stream>>>(cat0, wot, bo, ew, out,
                                                2048, 768, 256, 0);
}